// Round 1
// baseline (1951.450 us; speedup 1.0000x reference)
//
#include <hip/hip_runtime.h>
#include <math.h>

#define BATCH 4
#define CH    256
#define CQK   32
#define NPIX  4096   // 64*64

// ---------------------------------------------------------------------------
// Kernel 1: q/k/v 1x1-conv projections.
// Grid (128, 4): 32-pixel tile per block, batch in y. 256 threads.
// xs[n][c] staged in LDS (pad 260: 1040B rows -> 16B-aligned, stride 4 banks
// -> optimal 8-phase b128). 8 half-waves each own 40 of the 320 output rows,
// register-blocked 8 rows at a time so each xs float4 feeds 32 FMAs.
// ---------------------------------------------------------------------------
__global__ __launch_bounds__(256) void qkv_kernel(
    const float* __restrict__ x,
    const float* __restrict__ wq, const float* __restrict__ bq,
    const float* __restrict__ wk, const float* __restrict__ bk,
    const float* __restrict__ wv, const float* __restrict__ bv,
    float* __restrict__ Q, float* __restrict__ K, float* __restrict__ V)
{
    __shared__ float xs[32][260];

    const int b  = blockIdx.y;
    const int n0 = blockIdx.x * 32;
    const int t  = threadIdx.x;

    // load x[b][c][n0..n0+31] -> xs[n][c]; 8192 elems, coalesced 128B runs
    for (int rep = 0; rep < 32; ++rep) {
        int idx = rep * 256 + t;
        int c = idx >> 5, n = idx & 31;
        xs[n][c] = x[((size_t)b * CH + c) * NPIX + n0 + n];
    }
    __syncthreads();

    const int lane32 = t & 31;
    const int hg     = t >> 5;      // 8 half-wave groups

    for (int chunk = 0; chunk < 5; ++chunk) {
        int rbase = hg * 40 + chunk * 8;
        float acc[8];
        const float* wrow[8];
        float*       orow[8];
        #pragma unroll
        for (int k = 0; k < 8; ++k) {
            int r = rbase + k;
            if (r < 32) {
                wrow[k] = wq + r * CH;          acc[k] = bq[r];
                orow[k] = Q + ((size_t)b * CQK + r) * NPIX;
            } else if (r < 64) {
                wrow[k] = wk + (r - 32) * CH;   acc[k] = bk[r - 32];
                orow[k] = K + ((size_t)b * CQK + (r - 32)) * NPIX;
            } else {
                wrow[k] = wv + (r - 64) * CH;   acc[k] = bv[r - 64];
                orow[k] = V + ((size_t)b * CH + (r - 64)) * NPIX;
            }
        }
        for (int c4 = 0; c4 < 64; ++c4) {
            float4 xv = *(const float4*)&xs[lane32][c4 * 4];
            #pragma unroll
            for (int k = 0; k < 8; ++k) {
                float4 w4 = *(const float4*)&wrow[k][c4 * 4];
                acc[k] += w4.x * xv.x + w4.y * xv.y + w4.z * xv.z + w4.w * xv.w;
            }
        }
        #pragma unroll
        for (int k = 0; k < 8; ++k) orow[k][n0 + lane32] = acc[k];
    }
}

// ---------------------------------------------------------------------------
// Kernel 2: fused flash attention + gamma*out + x epilogue.
// Grid (64, 4): one 64-query tile per block, 256 threads, TJ = 32 keys/iter.
// QK phase: half-wave (lane = j) owns 8 query rows; K-row in 32 regs,
//   q read as 2-way LDS broadcast; online softmax via 5-step __shfl_xor.
// PV phase: thread = channel c; V-row in 32 regs; P rows read as b128
//   broadcasts; acc[64] fp32 in regs (fully-unrolled indexing only).
// LDS 60KB total (fits the 64KB static limit), strides 36 floats = 144B:
//   16B-aligned, 4-bank lane stride -> clean 8-phase b128.
// ---------------------------------------------------------------------------
__global__ __launch_bounds__(256, 1) void attn_kernel(
    const float* __restrict__ Q, const float* __restrict__ K,
    const float* __restrict__ V, const float* __restrict__ x,
    const float* __restrict__ gamma, float* __restrict__ out)
{
    __shared__ float qs[64][36];    // [i_local][d]
    __shared__ float ks[32][36];    // [j_local][d]
    __shared__ float vs[256][36];   // [c][j_local]
    __shared__ float sP[64][36];    // [i_local][j_local]  (P values)
    __shared__ float sFac[64];
    __shared__ float sL[64];

    const int b    = blockIdx.y;
    const int i0   = blockIdx.x * 64;
    const int t    = threadIdx.x;
    const int lane = t & 63;
    const int g    = t >> 6;         // wave 0..3
    const int half = (lane >> 5);    // 0/1
    const int jl   = lane & 31;      // j within tile (QK phase)

    // ---- load Q tile (transpose to qs[i][d]) ----
    #pragma unroll
    for (int rep = 0; rep < 2; ++rep) {
        int idx = rep * 256 + t;          // 0..511 float4s
        int d = idx >> 4, i4 = idx & 15;
        float4 q4 = *(const float4*)&Q[((size_t)b * CQK + d) * NPIX + i0 + i4 * 4];
        qs[i4 * 4 + 0][d] = q4.x;
        qs[i4 * 4 + 1][d] = q4.y;
        qs[i4 * 4 + 2][d] = q4.z;
        qs[i4 * 4 + 3][d] = q4.w;
    }

    float m_run[8], l_run[8];
    #pragma unroll
    for (int ii = 0; ii < 8; ++ii) { m_run[ii] = -1e30f; l_run[ii] = 0.f; }
    float acc[64];
    #pragma unroll
    for (int i = 0; i < 64; ++i) acc[i] = 0.f;
    const int c = t;   // PV mapping: thread owns channel c

    for (int jt = 0; jt < NPIX / 32; ++jt) {
        const int j0 = jt * 32;
        __syncthreads();   // prev PV done before tiles are overwritten

        // K tile -> ks[j][d] (transposed): 256 float4s, one per thread
        {
            int d = t >> 3, j4 = t & 7;
            float4 k4 = *(const float4*)&K[((size_t)b * CQK + d) * NPIX + j0 + j4 * 4];
            ks[j4 * 4 + 0][d] = k4.x;
            ks[j4 * 4 + 1][d] = k4.y;
            ks[j4 * 4 + 2][d] = k4.z;
            ks[j4 * 4 + 3][d] = k4.w;
        }
        // V tile -> vs[c][j]: 2048 float4s
        #pragma unroll
        for (int rep = 0; rep < 8; ++rep) {
            int idx = rep * 256 + t;
            int cc = idx >> 3, j4 = idx & 7;
            float4 v4 = *(const float4*)&V[((size_t)b * CH + cc) * NPIX + j0 + j4 * 4];
            *(float4*)&vs[cc][j4 * 4] = v4;
        }
        __syncthreads();

        // ---- QK^T + online softmax ----
        float kv[32];
        #pragma unroll
        for (int d4 = 0; d4 < 8; ++d4) {
            float4 kk = *(const float4*)&ks[jl][d4 * 4];
            kv[d4*4+0] = kk.x; kv[d4*4+1] = kk.y; kv[d4*4+2] = kk.z; kv[d4*4+3] = kk.w;
        }
        #pragma unroll
        for (int ii = 0; ii < 8; ++ii) {
            int i = (g << 4) + (half << 3) + ii;
            float s = 0.f;
            #pragma unroll
            for (int d4 = 0; d4 < 8; ++d4) {
                float4 qq = *(const float4*)&qs[i][d4 * 4];
                s += qq.x*kv[d4*4] + qq.y*kv[d4*4+1] + qq.z*kv[d4*4+2] + qq.w*kv[d4*4+3];
            }
            float mt = s;
            #pragma unroll
            for (int off = 1; off <= 16; off <<= 1)
                mt = fmaxf(mt, __shfl_xor(mt, off));
            float m_new = fmaxf(m_run[ii], mt);
            float fac   = __expf(m_run[ii] - m_new);
            float p     = __expf(s - m_new);
            float lt = p;
            #pragma unroll
            for (int off = 1; off <= 16; off <<= 1)
                lt += __shfl_xor(lt, off);
            l_run[ii] = l_run[ii] * fac + lt;
            m_run[ii] = m_new;
            sP[i][jl] = p;
            if (jl == 0) sFac[i] = fac;
        }
        __syncthreads();

        // ---- PV accumulate (thread = channel c) ----
        float vv[32];
        #pragma unroll
        for (int j4 = 0; j4 < 8; ++j4) {
            float4 v4 = *(const float4*)&vs[c][j4 * 4];
            vv[j4*4+0] = v4.x; vv[j4*4+1] = v4.y; vv[j4*4+2] = v4.z; vv[j4*4+3] = v4.w;
        }
        #pragma unroll
        for (int i = 0; i < 64; ++i) {
            float a = acc[i] * sFac[i];
            #pragma unroll
            for (int j4 = 0; j4 < 8; ++j4) {
                float4 p4 = *(const float4*)&sP[i][j4 * 4];
                a += p4.x*vv[j4*4] + p4.y*vv[j4*4+1] + p4.z*vv[j4*4+2] + p4.w*vv[j4*4+3];
            }
            acc[i] = a;
        }
    }

    // ---- publish softmax denominators ----
    if (jl == 0) {
        #pragma unroll
        for (int ii = 0; ii < 8; ++ii) {
            int i = (g << 4) + (half << 3) + ii;
            sL[i] = l_run[ii];
        }
    }
    __syncthreads();

    // ---- epilogue: out = gamma * (acc/l) + x ----
    const float gm = gamma[0];
    const size_t base = ((size_t)b * CH + c) * (size_t)NPIX + i0;
    #pragma unroll
    for (int i = 0; i < 64; ++i) {
        float o = acc[i] / sL[i];
        out[base + i] = gm * o + x[base + i];
    }
}

extern "C" void kernel_launch(void* const* d_in, const int* in_sizes, int n_in,
                              void* d_out, int out_size, void* d_ws, size_t ws_size,
                              hipStream_t stream) {
    const float* x     = (const float*)d_in[0];
    const float* wq    = (const float*)d_in[1];
    const float* bq    = (const float*)d_in[2];
    const float* wk    = (const float*)d_in[3];
    const float* bk    = (const float*)d_in[4];
    const float* wv    = (const float*)d_in[5];
    const float* bv    = (const float*)d_in[6];
    const float* gamma = (const float*)d_in[7];
    float* out = (float*)d_out;

    // workspace: Q (2MB) | K (2MB) | V (16MB) = 20MB
    float* Q = (float*)d_ws;
    float* K = Q + (size_t)BATCH * CQK * NPIX;
    float* V = K + (size_t)BATCH * CQK * NPIX;

    qkv_kernel<<<dim3(128, 4), 256, 0, stream>>>(x, wq, bq, wk, bk, wv, bv, Q, K, V);
    attn_kernel<<<dim3(64, 4), 256, 0, stream>>>(Q, K, V, x, gamma, out);
}

// Round 2
// 303.369 us; speedup vs baseline: 6.4326x; 6.4326x over previous
//
#include <hip/hip_runtime.h>
#include <math.h>

#define BATCH 4
#define CH    256
#define CQK   32
#define NPIX  4096   // 64*64

typedef __attribute__((ext_vector_type(8))) short short8;   // 8 bf16 (4 VGPRs)
typedef __attribute__((ext_vector_type(4))) float f32x4;

static __device__ __forceinline__ unsigned short f2bf(float f) {
    unsigned u = __builtin_bit_cast(unsigned, f);
    u = (u + 0x7fffu + ((u >> 16) & 1u)) >> 16;   // RNE
    return (unsigned short)u;
}
static __device__ __forceinline__ float bf2f(unsigned short s) {
    unsigned u = ((unsigned)s) << 16;
    return __builtin_bit_cast(float, u);
}
static __device__ __forceinline__ unsigned pack2(float a, float b) {
    return (unsigned)f2bf(a) | ((unsigned)f2bf(b) << 16);
}

// ---------------------------------------------------------------------------
// Kernel 1: q/k/v projections -> bf16 workspace.
//   Qh/Ql, Kh/Kl : [B][NPIX][32]  (pixel-major; hi+lo bf16 split of fp32)
//   Vb           : [B][CH][NPIX]  (channel-major, single bf16)
// ---------------------------------------------------------------------------
__global__ __launch_bounds__(256) void qkv_kernel(
    const float* __restrict__ x,
    const float* __restrict__ wq, const float* __restrict__ bq,
    const float* __restrict__ wk, const float* __restrict__ bk,
    const float* __restrict__ wv, const float* __restrict__ bv,
    unsigned short* __restrict__ Qh, unsigned short* __restrict__ Ql,
    unsigned short* __restrict__ Kh, unsigned short* __restrict__ Kl,
    unsigned short* __restrict__ Vb)
{
    __shared__ float xs[32][260];

    const int b  = blockIdx.y;
    const int n0 = blockIdx.x * 32;
    const int t  = threadIdx.x;

    for (int rep = 0; rep < 32; ++rep) {
        int idx = rep * 256 + t;
        int c = idx >> 5, n = idx & 31;
        xs[n][c] = x[((size_t)b * CH + c) * NPIX + n0 + n];
    }
    __syncthreads();

    const int lane32 = t & 31;
    const int hg     = t >> 5;
    const int n      = n0 + lane32;

    for (int chunk = 0; chunk < 5; ++chunk) {
        int rbase = hg * 40 + chunk * 8;      // multiple of 8, never straddles q/k/v
        float acc[8];
        const float* wrow[8];
        #pragma unroll
        for (int k = 0; k < 8; ++k) {
            int r = rbase + k;
            if (r < 32)      { wrow[k] = wq + r * CH;        acc[k] = bq[r]; }
            else if (r < 64) { wrow[k] = wk + (r - 32) * CH; acc[k] = bk[r - 32]; }
            else             { wrow[k] = wv + (r - 64) * CH; acc[k] = bv[r - 64]; }
        }
        for (int c4 = 0; c4 < 64; ++c4) {
            float4 xv = *(const float4*)&xs[lane32][c4 * 4];
            #pragma unroll
            for (int k = 0; k < 8; ++k) {
                float4 w4 = *(const float4*)&wrow[k][c4 * 4];
                acc[k] += w4.x * xv.x + w4.y * xv.y + w4.z * xv.z + w4.w * xv.w;
            }
        }
        if (rbase < 64) {
            union { unsigned short s[8]; uint4 v; } uh, ul;
            #pragma unroll
            for (int k = 0; k < 8; ++k) {
                unsigned short h = f2bf(acc[k]);
                uh.s[k] = h;
                ul.s[k] = f2bf(acc[k] - bf2f(h));
            }
            if (rbase < 32) {
                *(uint4*)&Qh[((size_t)b * NPIX + n) * CQK + rbase] = uh.v;
                *(uint4*)&Ql[((size_t)b * NPIX + n) * CQK + rbase] = ul.v;
            } else {
                *(uint4*)&Kh[((size_t)b * NPIX + n) * CQK + rbase - 32] = uh.v;
                *(uint4*)&Kl[((size_t)b * NPIX + n) * CQK + rbase - 32] = ul.v;
            }
        } else {
            #pragma unroll
            for (int k = 0; k < 8; ++k)
                Vb[((size_t)b * CH + (rbase - 64 + k)) * NPIX + n] = f2bf(acc[k]);
        }
    }
}

// ---------------------------------------------------------------------------
// Kernel 2: flash attention on MFMA, fully transposed formulation.
//   S' = K·Q^T  (mfma A=K[j][d], B=Q[i][d])  -> lane holds 4 consecutive j
//   P' stored [i][j] bf16 in XOR-swizzled LDS (b64 writes / b128 reads,
//   uniform bank load -> conflict-free)
//   O^T = V·P' (mfma A=V[c][j] direct from global/L2, B=P'[i][j] from LDS)
// 4 waves: wave w owns softmax rows i=w*16.. and output rows c=w*64..
// One barrier per KV step; P/fac double-buffered.
// ---------------------------------------------------------------------------
__global__ __launch_bounds__(256, 1) void attn_kernel(
    const unsigned short* __restrict__ Qh, const unsigned short* __restrict__ Ql,
    const unsigned short* __restrict__ Kh, const unsigned short* __restrict__ Kl,
    const unsigned short* __restrict__ Vb,
    const float* __restrict__ x, const float* __restrict__ gamma,
    float* __restrict__ out)
{
    __shared__ uint4 Pbuf[2][512];          // 2 x 8KB: P'[64 i][64 j] bf16, swizzled
    __shared__ float sFac[2][64];
    __shared__ float sL[64];

    // XCD-aware swizzle: 2 XCDs per batch -> each XCD's L2 holds one K/V set
    const int bid = blockIdx.x;
    const int b   = (bid & 7) >> 1;
    const int it  = (bid >> 3) + ((bid & 1) << 5);
    const int i0  = it * 64;

    const int t = threadIdx.x;
    const int w = t >> 6, l = t & 63, g = l >> 4, m = l & 15;

    // Q fragments (B operand: col = i, k = d), loaded once
    const int iq = i0 + w * 16 + m;
    const short8 qh = __builtin_bit_cast(short8, *(const uint4*)&Qh[((size_t)b * NPIX + iq) * CQK + g * 8]);
    const short8 ql = __builtin_bit_cast(short8, *(const uint4*)&Ql[((size_t)b * NPIX + iq) * CQK + g * 8]);

    f32x4 acc[4][4];
    #pragma unroll
    for (int cf = 0; cf < 4; ++cf)
        #pragma unroll
        for (int f = 0; f < 4; ++f) acc[cf][f] = (f32x4){0.f, 0.f, 0.f, 0.f};

    float m_run = -1e30f, l_run = 0.f;
    const int irow = w * 16 + m;

    for (int jt = 0; jt < NPIX / 64; ++jt) {
        const int j0  = jt * 64;
        const int idx = jt & 1;

        // ---- QK^T (compensated bf16: hi*hi + hi*lo + lo*hi) ----
        f32x4 sv[4];
        #pragma unroll
        for (int jf = 0; jf < 4; ++jf) {
            const size_t jr = ((size_t)b * NPIX + j0 + jf * 16 + m) * CQK + g * 8;
            short8 kh = __builtin_bit_cast(short8, *(const uint4*)&Kh[jr]);
            short8 kl = __builtin_bit_cast(short8, *(const uint4*)&Kl[jr]);
            f32x4 s = (f32x4){0.f, 0.f, 0.f, 0.f};
            s = __builtin_amdgcn_mfma_f32_16x16x32_bf16(kh, qh, s, 0, 0, 0);
            s = __builtin_amdgcn_mfma_f32_16x16x32_bf16(kh, ql, s, 0, 0, 0);
            s = __builtin_amdgcn_mfma_f32_16x16x32_bf16(kl, qh, s, 0, 0, 0);
            sv[jf] = s;
        }

        // ---- online softmax over j (lane's 16 regs + xor-16/32 across g) ----
        float tmax = sv[0][0];
        #pragma unroll
        for (int jf = 0; jf < 4; ++jf)
            #pragma unroll
            for (int r = 0; r < 4; ++r) tmax = fmaxf(tmax, sv[jf][r]);
        tmax = fmaxf(tmax, __shfl_xor(tmax, 16));
        tmax = fmaxf(tmax, __shfl_xor(tmax, 32));
        float m_new = fmaxf(m_run, tmax);
        float fac   = __expf(m_run - m_new);
        float pvv[4][4];
        float tsum = 0.f;
        #pragma unroll
        for (int jf = 0; jf < 4; ++jf)
            #pragma unroll
            for (int r = 0; r < 4; ++r) {
                float p = __expf(sv[jf][r] - m_new);
                pvv[jf][r] = p;
                tsum += p;
            }
        tsum += __shfl_xor(tsum, 16);
        tsum += __shfl_xor(tsum, 32);
        l_run = l_run * fac + tsum;
        m_run = m_new;
        if (g == 0) sFac[idx][irow] = fac;

        // ---- pack P -> bf16, swizzled LDS [i][j] ----
        {
            char* pb = (char*)Pbuf[idx];
            #pragma unroll
            for (int jf = 0; jf < 4; ++jf) {
                uint2 u;
                u.x = pack2(pvv[jf][0], pvv[jf][1]);
                u.y = pack2(pvv[jf][2], pvv[jf][3]);
                int off = (irow * 128 + jf * 32 + g * 8) ^ ((irow & 7) << 4);
                *(uint2*)(pb + off) = u;
            }
        }
        __syncthreads();

        // ---- PV: O^T[c][i] += V[c][j] * P'[j][i] ----
        short8 pf[4][2];
        float  ff[4];
        {
            const char* pb = (const char*)Pbuf[idx];
            #pragma unroll
            for (int f = 0; f < 4; ++f) {
                #pragma unroll
                for (int ks = 0; ks < 2; ++ks) {
                    int off = ((f * 16 + m) * 128 + g * 16 + ks * 64) ^ ((m & 7) << 4);
                    pf[f][ks] = __builtin_bit_cast(short8, *(const uint4*)(pb + off));
                }
                ff[f] = sFac[idx][f * 16 + m];
            }
        }
        #pragma unroll
        for (int cf = 0; cf < 4; ++cf) {
            const size_t crow = ((size_t)b * CH + w * 64 + cf * 16 + m) * NPIX + j0;
            short8 v0 = __builtin_bit_cast(short8, *(const uint4*)&Vb[crow + g * 8]);
            short8 v1 = __builtin_bit_cast(short8, *(const uint4*)&Vb[crow + 32 + g * 8]);
            #pragma unroll
            for (int f = 0; f < 4; ++f) {
                f32x4 a = acc[cf][f];
                a *= ff[f];
                a = __builtin_amdgcn_mfma_f32_16x16x32_bf16(v0, pf[f][0], a, 0, 0, 0);
                a = __builtin_amdgcn_mfma_f32_16x16x32_bf16(v1, pf[f][1], a, 0, 0, 0);
                acc[cf][f] = a;
            }
        }
    }

    // ---- epilogue: out = gamma * O/l + x ----
    if (g == 0) sL[irow] = l_run;
    __syncthreads();
    const float gm = gamma[0];
    #pragma unroll
    for (int f = 0; f < 4; ++f) {
        float linv = 1.0f / sL[f * 16 + m];
        #pragma unroll
        for (int cf = 0; cf < 4; ++cf) {
            #pragma unroll
            for (int r = 0; r < 4; ++r) {
                int c = w * 64 + cf * 16 + g * 4 + r;
                size_t o = ((size_t)b * CH + c) * NPIX + i0 + f * 16 + m;
                out[o] = gm * acc[cf][f][r] * linv + x[o];
            }
        }
    }
}

extern "C" void kernel_launch(void* const* d_in, const int* in_sizes, int n_in,
                              void* d_out, int out_size, void* d_ws, size_t ws_size,
                              hipStream_t stream) {
    const float* x     = (const float*)d_in[0];
    const float* wq    = (const float*)d_in[1];
    const float* bq    = (const float*)d_in[2];
    const float* wk    = (const float*)d_in[3];
    const float* bk    = (const float*)d_in[4];
    const float* wv    = (const float*)d_in[5];
    const float* bv    = (const float*)d_in[6];
    const float* gamma = (const float*)d_in[7];
    float* out = (float*)d_out;

    // bf16 workspace: Qh | Ql | Kh | Kl (1MB each) | Vb (8MB) = 12MB
    unsigned short* base = (unsigned short*)d_ws;
    const size_t qk_sz = (size_t)BATCH * NPIX * CQK;   // 524288
    unsigned short* Qh = base;
    unsigned short* Ql = Qh + qk_sz;
    unsigned short* Kh = Ql + qk_sz;
    unsigned short* Kl = Kh + qk_sz;
    unsigned short* Vb = Kl + qk_sz;

    qkv_kernel<<<dim3(128, 4), 256, 0, stream>>>(x, wq, bq, wk, bk, wv, bv,
                                                 Qh, Ql, Kh, Kl, Vb);
    attn_kernel<<<256, 256, 0, stream>>>(Qh, Ql, Kh, Kl, Vb, x, gamma, out);
}

// Round 3
// 173.090 us; speedup vs baseline: 11.2742x; 1.7527x over previous
//
#include <hip/hip_runtime.h>
#include <math.h>

#define BATCH 4
#define CH    256
#define CQK   32
#define NPIX  4096   // 64*64

typedef __attribute__((ext_vector_type(8))) short short8;   // 8 bf16 (4 VGPRs)
typedef __attribute__((ext_vector_type(4))) float f32x4;

static __device__ __forceinline__ unsigned short f2bf(float f) {
    unsigned u = __builtin_bit_cast(unsigned, f);
    u = (u + 0x7fffu + ((u >> 16) & 1u)) >> 16;   // RNE
    return (unsigned short)u;
}
static __device__ __forceinline__ float bf2f(unsigned short s) {
    unsigned u = ((unsigned)s) << 16;
    return __builtin_bit_cast(float, u);
}
static __device__ __forceinline__ unsigned pack2(float a, float b) {
    return (unsigned)f2bf(a) | ((unsigned)f2bf(b) << 16);
}

// ---------------------------------------------------------------------------
// Kernel 0: convert W (rows: 32 q | 32 k | 256 v, each x256) to bf16 hi/lo.
// ---------------------------------------------------------------------------
__global__ __launch_bounds__(256) void wcvt_kernel(
    const float* __restrict__ wq, const float* __restrict__ wk,
    const float* __restrict__ wv,
    unsigned short* __restrict__ Wh, unsigned short* __restrict__ Wl)
{
    int idx = blockIdx.x * 256 + threadIdx.x;   // 0..81919
    int r = idx >> 8, c = idx & 255;
    float f;
    if (r < 32)       f = wq[r * 256 + c];
    else if (r < 64)  f = wk[(r - 32) * 256 + c];
    else              f = wv[(r - 64) * 256 + c];
    unsigned short h = f2bf(f);
    Wh[idx] = h;
    Wl[idx] = f2bf(f - bf2f(h));
}

// ---------------------------------------------------------------------------
// Kernel 1: q/k/v projections as compensated-bf16 MFMA GEMM.
//   D[320 rows][n] = W[320][256] * X[256][n], per-block n-tile = 32 pixels.
//   X staged transposed in LDS (hi/lo planes, XOR-swizzled 512B rows).
//   Wave w owns rows w*80..w*80+79 (five 16-row d-tiles; tiles never
//   straddle the q/k/v boundaries at 32 and 64).
// Outputs: Qh/Ql,Kh/Kl [b][n][32]; Vb [b][c][n] (single bf16).
// ---------------------------------------------------------------------------
__global__ __launch_bounds__(256) void qkv_kernel(
    const float* __restrict__ x,
    const float* __restrict__ bq, const float* __restrict__ bk,
    const float* __restrict__ bv,
    const unsigned short* __restrict__ Wh, const unsigned short* __restrict__ Wl,
    unsigned short* __restrict__ Qh, unsigned short* __restrict__ Ql,
    unsigned short* __restrict__ Kh, unsigned short* __restrict__ Kl,
    unsigned short* __restrict__ Vb)
{
    __shared__ __align__(16) unsigned short Xh[32 * 256];  // swizzled [n][c]
    __shared__ __align__(16) unsigned short Xl[32 * 256];

    const int b  = blockIdx.y;
    const int n0 = blockIdx.x * 32;
    const int t  = threadIdx.x;

    // ---- stage x tile transposed, fp32 -> bf16 hi/lo, swizzled ----
    #pragma unroll
    for (int rep = 0; rep < 8; ++rep) {
        int idx = rep * 256 + t;       // float4 units
        int c = idx >> 3, n4 = idx & 7;
        float4 xv = *(const float4*)&x[((size_t)b * CH + c) * NPIX + n0 + n4 * 4];
        #pragma unroll
        for (int u = 0; u < 4; ++u) {
            int n = n4 * 4 + u;
            float f = (&xv.x)[u];
            unsigned short h = f2bf(f);
            unsigned short l = f2bf(f - bf2f(h));
            int off = n * 512 + (((c >> 3) * 16) ^ ((n & 7) << 4)) + (c & 7) * 2;
            *(unsigned short*)((char*)Xh + off) = h;
            *(unsigned short*)((char*)Xl + off) = l;
        }
    }
    __syncthreads();

    const int w = t >> 6, l = t & 63, g = l >> 4, m = l & 15;

    for (int dt = 0; dt < 5; ++dt) {
        const int d0 = w * 80 + dt * 16;

        // W fragments for all 8 k-steps (hi+lo), from L2
        short8 wh[8], wl[8];
        #pragma unroll
        for (int ks = 0; ks < 8; ++ks) {
            size_t off = (size_t)(d0 + m) * 256 + ks * 32 + g * 8;
            wh[ks] = __builtin_bit_cast(short8, *(const uint4*)&Wh[off]);
            wl[ks] = __builtin_bit_cast(short8, *(const uint4*)&Wl[off]);
        }

        f32x4 acc[2];
        acc[0] = (f32x4){0.f, 0.f, 0.f, 0.f};
        acc[1] = (f32x4){0.f, 0.f, 0.f, 0.f};
        #pragma unroll
        for (int nt = 0; nt < 2; ++nt) {
            const int n = nt * 16 + m;
            #pragma unroll
            for (int ks = 0; ks < 8; ++ks) {
                int off = n * 512 + (((ks * 4 + g) * 16) ^ ((n & 7) << 4));
                short8 xh = __builtin_bit_cast(short8, *(const uint4*)((char*)Xh + off));
                short8 xl = __builtin_bit_cast(short8, *(const uint4*)((char*)Xl + off));
                acc[nt] = __builtin_amdgcn_mfma_f32_16x16x32_bf16(wh[ks], xh, acc[nt], 0, 0, 0);
                acc[nt] = __builtin_amdgcn_mfma_f32_16x16x32_bf16(wh[ks], xl, acc[nt], 0, 0, 0);
                acc[nt] = __builtin_amdgcn_mfma_f32_16x16x32_bf16(wl[ks], xh, acc[nt], 0, 0, 0);
            }
        }

        // ---- bias + store ----
        int kind;                      // 0=Q, 1=K, 2=V
        float4 bias;
        if (d0 < 32)      { kind = 0; bias = *(const float4*)&bq[d0 + g * 4]; }
        else if (d0 < 64) { kind = 1; bias = *(const float4*)&bk[d0 - 32 + g * 4]; }
        else              { kind = 2; bias = *(const float4*)&bv[d0 - 64 + g * 4]; }

        #pragma unroll
        for (int nt = 0; nt < 2; ++nt) {
            const int n = n0 + nt * 16 + m;
            if (kind == 2) {
                const int c0 = d0 - 64;
                #pragma unroll
                for (int r = 0; r < 4; ++r) {
                    float val = acc[nt][r] + (&bias.x)[r];
                    Vb[((size_t)b * CH + c0 + g * 4 + r) * NPIX + n] = f2bf(val);
                }
            } else {
                unsigned short hs[4], ls[4];
                #pragma unroll
                for (int r = 0; r < 4; ++r) {
                    float val = acc[nt][r] + (&bias.x)[r];
                    unsigned short h = f2bf(val);
                    hs[r] = h;
                    ls[r] = f2bf(val - bf2f(h));
                }
                const int dcol = (d0 & 31) + g * 4;
                const size_t base = ((size_t)b * NPIX + n) * CQK + dcol;
                uint2 uh, ul;
                uh.x = (unsigned)hs[0] | ((unsigned)hs[1] << 16);
                uh.y = (unsigned)hs[2] | ((unsigned)hs[3] << 16);
                ul.x = (unsigned)ls[0] | ((unsigned)ls[1] << 16);
                ul.y = (unsigned)ls[2] | ((unsigned)ls[3] << 16);
                if (kind == 0) {
                    *(uint2*)&Qh[base] = uh;
                    *(uint2*)&Ql[base] = ul;
                } else {
                    *(uint2*)&Kh[base] = uh;
                    *(uint2*)&Kl[base] = ul;
                }
            }
        }
    }
}

// ---------------------------------------------------------------------------
// Kernel 2: flash attention on MFMA (transposed), K tile LDS-staged.
//   Per step: QK^T from LDS K tile -> issue next K tile global loads ->
//   softmax -> P pack/write -> ds_write next K tile -> barrier -> PV.
//   K LDS rows: j -> [hi 64B | lo 64B] = 128B, slots XOR-swizzled by (j&7).
// ---------------------------------------------------------------------------
__global__ __launch_bounds__(256, 1) void attn_kernel(
    const unsigned short* __restrict__ Qh, const unsigned short* __restrict__ Ql,
    const unsigned short* __restrict__ Kh, const unsigned short* __restrict__ Kl,
    const unsigned short* __restrict__ Vb,
    const float* __restrict__ x, const float* __restrict__ gamma,
    float* __restrict__ out)
{
    __shared__ __align__(16) char Ksw[2][8192];   // [j][hi|lo] swizzled
    __shared__ uint4 Pbuf[2][512];                // P'[64 i][64 j] bf16, swizzled
    __shared__ float sFac[2][64];
    __shared__ float sL[64];

    // XCD-aware swizzle: 2 XCDs per batch
    const int bid = blockIdx.x;
    const int b   = (bid & 7) >> 1;
    const int it  = (bid >> 3) + ((bid & 1) << 5);
    const int i0  = it * 64;

    const int t = threadIdx.x;
    const int w = t >> 6, l = t & 63, g = l >> 4, m = l & 15;

    // K-prefetch slot mapping for this thread (slots t and t+256 of 512)
    const int sj0 = t >> 3, sq0 = t & 7;
    const int pl0 = sq0 >> 2, gq0 = sq0 & 3;
    const unsigned short* kpl0 = pl0 ? Kl : Kh;
    const int wr0 = sj0 * 128 + ((sq0 * 16) ^ ((sj0 & 7) << 4));
    const int sj1 = sj0 + 32;
    const int wr1 = sj1 * 128 + ((sq0 * 16) ^ ((sj1 & 7) << 4));

    // Q fragments (held for the whole kernel)
    const int iq = i0 + w * 16 + m;
    const short8 qh = __builtin_bit_cast(short8, *(const uint4*)&Qh[((size_t)b * NPIX + iq) * CQK + g * 8]);
    const short8 ql = __builtin_bit_cast(short8, *(const uint4*)&Ql[((size_t)b * NPIX + iq) * CQK + g * 8]);

    f32x4 acc[4][4];
    #pragma unroll
    for (int cf = 0; cf < 4; ++cf)
        #pragma unroll
        for (int f = 0; f < 4; ++f) acc[cf][f] = (f32x4){0.f, 0.f, 0.f, 0.f};

    float m_run = -1e30f, l_run = 0.f;
    const int irow = w * 16 + m;

    // ---- prologue: stage K tile 0 into Ksw[0] ----
    {
        const size_t rb = ((size_t)b * NPIX + sj0) * CQK + gq0 * 8;
        uint4 k0 = *(const uint4*)&kpl0[rb];
        uint4 k1 = *(const uint4*)&kpl0[rb + 32 * CQK];
        *(uint4*)&Ksw[0][wr0] = k0;
        *(uint4*)&Ksw[0][wr1] = k1;
    }
    __syncthreads();

    for (int jt = 0; jt < NPIX / 64; ++jt) {
        const int j0  = jt * 64;
        const int idx = jt & 1;

        // ---- QK^T from LDS (compensated bf16) ----
        f32x4 sv[4];
        #pragma unroll
        for (int jf = 0; jf < 4; ++jf) {
            const int j = jf * 16 + m;
            short8 kh = __builtin_bit_cast(short8,
                *(const uint4*)&Ksw[idx][j * 128 + ((g * 16) ^ ((j & 7) << 4))]);
            short8 kl = __builtin_bit_cast(short8,
                *(const uint4*)&Ksw[idx][j * 128 + (((4 + g) * 16) ^ ((j & 7) << 4))]);
            f32x4 s = (f32x4){0.f, 0.f, 0.f, 0.f};
            s = __builtin_amdgcn_mfma_f32_16x16x32_bf16(kh, qh, s, 0, 0, 0);
            s = __builtin_amdgcn_mfma_f32_16x16x32_bf16(kh, ql, s, 0, 0, 0);
            s = __builtin_amdgcn_mfma_f32_16x16x32_bf16(kl, qh, s, 0, 0, 0);
            sv[jf] = s;
        }

        // ---- issue global loads for next K tile (latency hidden by softmax)
        uint4 pk0, pk1;
        {
            const size_t rb = ((size_t)b * NPIX + j0 + 64 + sj0) * CQK + gq0 * 8;
            pk0 = *(const uint4*)&kpl0[rb];
            pk1 = *(const uint4*)&kpl0[rb + 32 * CQK];
        }

        // ---- online softmax over j ----
        float tmax = sv[0][0];
        #pragma unroll
        for (int jf = 0; jf < 4; ++jf)
            #pragma unroll
            for (int r = 0; r < 4; ++r) tmax = fmaxf(tmax, sv[jf][r]);
        tmax = fmaxf(tmax, __shfl_xor(tmax, 16));
        tmax = fmaxf(tmax, __shfl_xor(tmax, 32));
        float m_new = fmaxf(m_run, tmax);
        float fac   = __expf(m_run - m_new);
        float pvv[4][4];
        float tsum = 0.f;
        #pragma unroll
        for (int jf = 0; jf < 4; ++jf)
            #pragma unroll
            for (int r = 0; r < 4; ++r) {
                float p = __expf(sv[jf][r] - m_new);
                pvv[jf][r] = p;
                tsum += p;
            }
        tsum += __shfl_xor(tsum, 16);
        tsum += __shfl_xor(tsum, 32);
        l_run = l_run * fac + tsum;
        m_run = m_new;
        if (g == 0) sFac[idx][irow] = fac;

        // ---- pack P -> bf16, swizzled LDS [i][j] ----
        {
            char* pb = (char*)Pbuf[idx];
            #pragma unroll
            for (int jf = 0; jf < 4; ++jf) {
                uint2 u;
                u.x = pack2(pvv[jf][0], pvv[jf][1]);
                u.y = pack2(pvv[jf][2], pvv[jf][3]);
                int off = (irow * 128 + jf * 32 + g * 8) ^ ((irow & 7) << 4);
                *(uint2*)(pb + off) = u;
            }
        }

        // ---- write prefetched K tile into the other buffer ----
        *(uint4*)&Ksw[idx ^ 1][wr0] = pk0;
        *(uint4*)&Ksw[idx ^ 1][wr1] = pk1;

        __syncthreads();

        // ---- PV: O^T[c][i] += V[c][j] * P'[j][i] ----
        short8 pf[4][2];
        float  ff[4];
        {
            const char* pb = (const char*)Pbuf[idx];
            #pragma unroll
            for (int f = 0; f < 4; ++f) {
                #pragma unroll
                for (int ks = 0; ks < 2; ++ks) {
                    int off = ((f * 16 + m) * 128 + g * 16 + ks * 64) ^ ((m & 7) << 4);
                    pf[f][ks] = __builtin_bit_cast(short8, *(const uint4*)(pb + off));
                }
                ff[f] = sFac[idx][f * 16 + m];
            }
        }
        #pragma unroll
        for (int cf = 0; cf < 4; ++cf) {
            const size_t crow = ((size_t)b * CH + w * 64 + cf * 16 + m) * NPIX + j0;
            short8 v0 = __builtin_bit_cast(short8, *(const uint4*)&Vb[crow + g * 8]);
            short8 v1 = __builtin_bit_cast(short8, *(const uint4*)&Vb[crow + 32 + g * 8]);
            #pragma unroll
            for (int f = 0; f < 4; ++f) {
                f32x4 a = acc[cf][f];
                a *= ff[f];
                a = __builtin_amdgcn_mfma_f32_16x16x32_bf16(v0, pf[f][0], a, 0, 0, 0);
                a = __builtin_amdgcn_mfma_f32_16x16x32_bf16(v1, pf[f][1], a, 0, 0, 0);
                acc[cf][f] = a;
            }
        }
    }

    // ---- epilogue: out = gamma * O/l + x ----
    if (g == 0) sL[irow] = l_run;
    __syncthreads();
    const float gm = gamma[0];
    #pragma unroll
    for (int f = 0; f < 4; ++f) {
        float linv = 1.0f / sL[f * 16 + m];
        #pragma unroll
        for (int cf = 0; cf < 4; ++cf) {
            #pragma unroll
            for (int r = 0; r < 4; ++r) {
                int c = w * 64 + cf * 16 + g * 4 + r;
                size_t o = ((size_t)b * CH + c) * NPIX + i0 + f * 16 + m;
                out[o] = gm * acc[cf][f][r] * linv + x[o];
            }
        }
    }
}

extern "C" void kernel_launch(void* const* d_in, const int* in_sizes, int n_in,
                              void* d_out, int out_size, void* d_ws, size_t ws_size,
                              hipStream_t stream) {
    const float* x     = (const float*)d_in[0];
    const float* wq    = (const float*)d_in[1];
    const float* bq    = (const float*)d_in[2];
    const float* wk    = (const float*)d_in[3];
    const float* bk    = (const float*)d_in[4];
    const float* wv    = (const float*)d_in[5];
    const float* bv    = (const float*)d_in[6];
    const float* gamma = (const float*)d_in[7];
    float* out = (float*)d_out;

    // ws layout (bf16): Qh|Ql|Kh|Kl (1MB each) | Vb (8MB) | Wh|Wl (160KB each)
    unsigned short* base = (unsigned short*)d_ws;
    const size_t qk_sz = (size_t)BATCH * NPIX * CQK;   // 524288
    unsigned short* Qh = base;
    unsigned short* Ql = Qh + qk_sz;
    unsigned short* Kh = Ql + qk_sz;
    unsigned short* Kl = Kh + qk_sz;
    unsigned short* Vb = Kl + qk_sz;
    unsigned short* Wh = Vb + (size_t)BATCH * CH * NPIX;
    unsigned short* Wl = Wh + 320 * 256;

    wcvt_kernel<<<320, 256, 0, stream>>>(wq, wk, wv, Wh, Wl);
    qkv_kernel<<<dim3(128, 4), 256, 0, stream>>>(x, bq, bk, bv, Wh, Wl,
                                                 Qh, Ql, Kh, Kl, Vb);
    attn_kernel<<<256, 256, 0, stream>>>(Qh, Ql, Kh, Kl, Vb, x, gamma, out);
}

// Round 4
// 140.035 us; speedup vs baseline: 13.9355x; 1.2360x over previous
//
#include <hip/hip_runtime.h>
#include <math.h>

#define BATCH 4
#define CH    256
#define CQK   32
#define NPIX  4096   // 64*64
#define LOG2E 1.4426950408889634f

typedef __attribute__((ext_vector_type(8))) short short8;   // 8 bf16 (4 VGPRs)
typedef __attribute__((ext_vector_type(4))) float f32x4;

static __device__ __forceinline__ unsigned short f2bf(float f) {
    unsigned u = __builtin_bit_cast(unsigned, f);
    u = (u + 0x7fffu + ((u >> 16) & 1u)) >> 16;   // RNE
    return (unsigned short)u;
}
static __device__ __forceinline__ float bf2f(unsigned short s) {
    unsigned u = ((unsigned)s) << 16;
    return __builtin_bit_cast(float, u);
}
static __device__ __forceinline__ float exp2_fast(float x) {
    float r; asm("v_exp_f32 %0, %1" : "=v"(r) : "v"(x)); return r;
}
static __device__ __forceinline__ unsigned cvt_pk_bf16(float lo, float hi) {
    unsigned r; asm("v_cvt_pk_bf16_f32 %0, %1, %2" : "=v"(r) : "v"(lo), "v"(hi)); return r;
}

// ---------------------------------------------------------------------------
// Kernel 0: W -> bf16 hi/lo. Q rows pre-scaled by log2(e) (base-2 softmax).
// ---------------------------------------------------------------------------
__global__ __launch_bounds__(256) void wcvt_kernel(
    const float* __restrict__ wq, const float* __restrict__ wk,
    const float* __restrict__ wv,
    unsigned short* __restrict__ Wh, unsigned short* __restrict__ Wl)
{
    int idx = blockIdx.x * 256 + threadIdx.x;   // 0..81919
    int r = idx >> 8, c = idx & 255;
    float f;
    if (r < 32)       f = wq[r * 256 + c] * LOG2E;
    else if (r < 64)  f = wk[(r - 32) * 256 + c];
    else              f = wv[(r - 64) * 256 + c];
    unsigned short h = f2bf(f);
    Wh[idx] = h;
    Wl[idx] = f2bf(f - bf2f(h));
}

// ---------------------------------------------------------------------------
// Kernel 1: q/k/v projections as compensated-bf16 MFMA GEMM (unchanged
// structure; q bias scaled by log2e to match scaled Wq).
// ---------------------------------------------------------------------------
__global__ __launch_bounds__(256) void qkv_kernel(
    const float* __restrict__ x,
    const float* __restrict__ bq, const float* __restrict__ bk,
    const float* __restrict__ bv,
    const unsigned short* __restrict__ Wh, const unsigned short* __restrict__ Wl,
    unsigned short* __restrict__ Qh, unsigned short* __restrict__ Ql,
    unsigned short* __restrict__ Kh, unsigned short* __restrict__ Kl,
    unsigned short* __restrict__ Vb)
{
    __shared__ __align__(16) unsigned short Xh[32 * 256];  // swizzled [n][c]
    __shared__ __align__(16) unsigned short Xl[32 * 256];

    const int b  = blockIdx.y;
    const int n0 = blockIdx.x * 32;
    const int t  = threadIdx.x;

    #pragma unroll
    for (int rep = 0; rep < 8; ++rep) {
        int idx = rep * 256 + t;       // float4 units
        int c = idx >> 3, n4 = idx & 7;
        float4 xv = *(const float4*)&x[((size_t)b * CH + c) * NPIX + n0 + n4 * 4];
        #pragma unroll
        for (int u = 0; u < 4; ++u) {
            int n = n4 * 4 + u;
            float f = (&xv.x)[u];
            unsigned short h = f2bf(f);
            unsigned short l = f2bf(f - bf2f(h));
            int off = n * 512 + (((c >> 3) * 16) ^ ((n & 7) << 4)) + (c & 7) * 2;
            *(unsigned short*)((char*)Xh + off) = h;
            *(unsigned short*)((char*)Xl + off) = l;
        }
    }
    __syncthreads();

    const int w = t >> 6, l = t & 63, g = l >> 4, m = l & 15;

    for (int dt = 0; dt < 5; ++dt) {
        const int d0 = w * 80 + dt * 16;

        short8 wh[8], wl[8];
        #pragma unroll
        for (int ks = 0; ks < 8; ++ks) {
            size_t off = (size_t)(d0 + m) * 256 + ks * 32 + g * 8;
            wh[ks] = __builtin_bit_cast(short8, *(const uint4*)&Wh[off]);
            wl[ks] = __builtin_bit_cast(short8, *(const uint4*)&Wl[off]);
        }

        f32x4 acc[2];
        acc[0] = (f32x4){0.f, 0.f, 0.f, 0.f};
        acc[1] = (f32x4){0.f, 0.f, 0.f, 0.f};
        #pragma unroll
        for (int nt = 0; nt < 2; ++nt) {
            const int n = nt * 16 + m;
            #pragma unroll
            for (int ks = 0; ks < 8; ++ks) {
                int off = n * 512 + (((ks * 4 + g) * 16) ^ ((n & 7) << 4));
                short8 xh = __builtin_bit_cast(short8, *(const uint4*)((char*)Xh + off));
                short8 xl = __builtin_bit_cast(short8, *(const uint4*)((char*)Xl + off));
                acc[nt] = __builtin_amdgcn_mfma_f32_16x16x32_bf16(wh[ks], xh, acc[nt], 0, 0, 0);
                acc[nt] = __builtin_amdgcn_mfma_f32_16x16x32_bf16(wh[ks], xl, acc[nt], 0, 0, 0);
                acc[nt] = __builtin_amdgcn_mfma_f32_16x16x32_bf16(wl[ks], xh, acc[nt], 0, 0, 0);
            }
        }

        int kind;                      // 0=Q, 1=K, 2=V
        float4 bias;
        if (d0 < 32)      { kind = 0; bias = *(const float4*)&bq[d0 + g * 4];
                            bias.x *= LOG2E; bias.y *= LOG2E; bias.z *= LOG2E; bias.w *= LOG2E; }
        else if (d0 < 64) { kind = 1; bias = *(const float4*)&bk[d0 - 32 + g * 4]; }
        else              { kind = 2; bias = *(const float4*)&bv[d0 - 64 + g * 4]; }

        #pragma unroll
        for (int nt = 0; nt < 2; ++nt) {
            const int n = n0 + nt * 16 + m;
            if (kind == 2) {
                const int c0 = d0 - 64;
                #pragma unroll
                for (int r = 0; r < 4; ++r) {
                    float val = acc[nt][r] + (&bias.x)[r];
                    Vb[((size_t)b * CH + c0 + g * 4 + r) * NPIX + n] = f2bf(val);
                }
            } else {
                unsigned short hs[4], ls[4];
                #pragma unroll
                for (int r = 0; r < 4; ++r) {
                    float val = acc[nt][r] + (&bias.x)[r];
                    unsigned short h = f2bf(val);
                    hs[r] = h;
                    ls[r] = f2bf(val - bf2f(h));
                }
                const int dcol = (d0 & 31) + g * 4;
                const size_t base = ((size_t)b * NPIX + n) * CQK + dcol;
                uint2 uh, ul;
                uh.x = (unsigned)hs[0] | ((unsigned)hs[1] << 16);
                uh.y = (unsigned)hs[2] | ((unsigned)hs[3] << 16);
                ul.x = (unsigned)ls[0] | ((unsigned)ls[1] << 16);
                ul.y = (unsigned)ls[2] | ((unsigned)ls[3] << 16);
                if (kind == 0) {
                    *(uint2*)&Qh[base] = uh;
                    *(uint2*)&Ql[base] = ul;
                } else {
                    *(uint2*)&Kh[base] = uh;
                    *(uint2*)&Kl[base] = ul;
                }
            }
        }
    }
}

// ---------------------------------------------------------------------------
// Kernel 2: flash attention, producer/consumer wave specialization.
//   512 threads: waves 0-3 = producers (QK^T + softmax + P pack),
//   waves 4-7 = consumers (PV MFMA + K/V prefetch + epilogue).
//   Double-buffered Ksw/Pbuf/sFac; ONE __syncthreads per KV step.
//   Base-2 online softmax with defer-max (threshold 11.5 in log2 units).
// ---------------------------------------------------------------------------
__global__ __launch_bounds__(512, 2) void attn_kernel(
    const unsigned short* __restrict__ Qh, const unsigned short* __restrict__ Ql,
    const unsigned short* __restrict__ Kh, const unsigned short* __restrict__ Kl,
    const unsigned short* __restrict__ Vb,
    const float* __restrict__ x, const float* __restrict__ gamma,
    float* __restrict__ out)
{
    __shared__ __align__(16) char Ksw[2][8192];   // K tile [j][hi|lo] swizzled
    __shared__ uint4 Pbuf[2][512];                // P'[64 i][64 j] bf16, swizzled
    __shared__ float sFac[2][64];
    __shared__ float sL[64];

    // XCD-aware swizzle: 2 XCDs per batch
    const int bid = blockIdx.x;
    const int b   = (bid & 7) >> 1;
    const int it  = (bid >> 3) + ((bid & 1) << 5);
    const int i0  = it * 64;

    const int t   = threadIdx.x;
    const int wv8 = t >> 6;                  // 0..7
    const bool isProd = (wv8 < 4);
    const int w   = wv8 & 3;                 // role-local wave id
    const int l   = t & 63, g = l >> 4, m = l & 15;
    const int irow = w * 16 + m;

    // ---- cooperative K tile 0 staging: 512 slots, one uint4 per thread ----
    {
        int sj = t >> 3, sq = t & 7;
        const unsigned short* kp = (sq >> 2) ? Kl : Kh;
        int wr = sj * 128 + ((sq * 16) ^ ((sj & 7) << 4));
        *(uint4*)&Ksw[0][wr] =
            *(const uint4*)&kp[((size_t)b * NPIX + sj) * CQK + (sq & 3) * 8];
    }

    // ---- producer state ----
    short8 qh = {}, ql = {};
    float m_run = -1e30f, l_run = 0.f;
    int pwoff[4];
    if (isProd) {
        const int iq = i0 + irow;
        qh = __builtin_bit_cast(short8, *(const uint4*)&Qh[((size_t)b * NPIX + iq) * CQK + g * 8]);
        ql = __builtin_bit_cast(short8, *(const uint4*)&Ql[((size_t)b * NPIX + iq) * CQK + g * 8]);
        #pragma unroll
        for (int jf = 0; jf < 4; ++jf)
            pwoff[jf] = (irow * 128 + jf * 32 + g * 8) ^ ((irow & 7) << 4);
    }

    // ---- consumer state ----
    f32x4 acc[4][4];
    #pragma unroll
    for (int cf = 0; cf < 4; ++cf)
        #pragma unroll
        for (int f = 0; f < 4; ++f) acc[cf][f] = (f32x4){0.f, 0.f, 0.f, 0.f};
    const unsigned short* vbase[4];
    uint4 vcur[8];
    int pr_off[4][2];
    int kwr0 = 0, kwr1 = 0;
    const unsigned short* kpfx = Kh;
    size_t kpf_base = 0;
    if (!isProd) {
        #pragma unroll
        for (int cf = 0; cf < 4; ++cf) {
            vbase[cf] = Vb + ((size_t)b * CH + w * 64 + cf * 16 + m) * NPIX;
            vcur[cf * 2]     = *(const uint4*)&vbase[cf][g * 8];
            vcur[cf * 2 + 1] = *(const uint4*)&vbase[cf][32 + g * 8];
        }
        #pragma unroll
        for (int f = 0; f < 4; ++f) {
            pr_off[f][0] = ((f * 16 + m) * 128 + g * 16)      ^ ((m & 7) << 4);
            pr_off[f][1] = ((f * 16 + m) * 128 + g * 16 + 64) ^ ((m & 7) << 4);
        }
        const int t2 = t & 255;
        const int sj0 = t2 >> 3, sq0 = t2 & 7;
        kpfx = (sq0 >> 2) ? Kl : Kh;
        kpf_base = ((size_t)b * NPIX + sj0) * CQK + (sq0 & 3) * 8;
        kwr0 = sj0 * 128 + ((sq0 * 16) ^ ((sj0 & 7) << 4));
        const int sj1 = sj0 + 32;
        kwr1 = sj1 * 128 + ((sq0 * 16) ^ ((sj1 & 7) << 4));
    }

    __syncthreads();

    for (int jt = 0; jt <= 64; ++jt) {
        const int idx = jt & 1;

        if (isProd && jt < 64) {
            // ---- QK^T (compensated bf16, base-2 scaled) ----
            f32x4 sv[4];
            #pragma unroll
            for (int jf = 0; jf < 4; ++jf) {
                const int j = jf * 16 + m;
                short8 kh = __builtin_bit_cast(short8,
                    *(const uint4*)&Ksw[idx][j * 128 + ((g * 16) ^ ((j & 7) << 4))]);
                short8 kl = __builtin_bit_cast(short8,
                    *(const uint4*)&Ksw[idx][j * 128 + (((4 + g) * 16) ^ ((j & 7) << 4))]);
                f32x4 s = (f32x4){0.f, 0.f, 0.f, 0.f};
                s = __builtin_amdgcn_mfma_f32_16x16x32_bf16(kh, qh, s, 0, 0, 0);
                s = __builtin_amdgcn_mfma_f32_16x16x32_bf16(kh, ql, s, 0, 0, 0);
                s = __builtin_amdgcn_mfma_f32_16x16x32_bf16(kl, qh, s, 0, 0, 0);
                sv[jf] = s;
            }

            // ---- tree max ----
            float s16[16];
            #pragma unroll
            for (int jf = 0; jf < 4; ++jf)
                #pragma unroll
                for (int r = 0; r < 4; ++r) s16[jf * 4 + r] = sv[jf][r];
            float mx[8];
            #pragma unroll
            for (int k = 0; k < 8; ++k) mx[k] = fmaxf(s16[k], s16[k + 8]);
            #pragma unroll
            for (int k = 0; k < 4; ++k) mx[k] = fmaxf(mx[k], mx[k + 4]);
            float tmax = fmaxf(fmaxf(mx[0], mx[2]), fmaxf(mx[1], mx[3]));
            tmax = fmaxf(tmax, __shfl_xor(tmax, 16));
            tmax = fmaxf(tmax, __shfl_xor(tmax, 32));

            // ---- defer-max: keep old max unless it grew by > 11.5 (log2) ----
            const bool keep = (tmax <= m_run + 11.5f);
            const float mt  = keep ? m_run : tmax;
            const float fac = keep ? 1.0f : exp2_fast(m_run - tmax);

            float p[16];
            #pragma unroll
            for (int k = 0; k < 16; ++k) p[k] = exp2_fast(s16[k] - mt);
            float sm[8];
            #pragma unroll
            for (int k = 0; k < 8; ++k) sm[k] = p[k] + p[k + 8];
            #pragma unroll
            for (int k = 0; k < 4; ++k) sm[k] = sm[k] + sm[k + 4];
            float tsum = (sm[0] + sm[2]) + (sm[1] + sm[3]);
            tsum += __shfl_xor(tsum, 16);
            tsum += __shfl_xor(tsum, 32);

            l_run = l_run * fac + tsum;
            m_run = mt;
            if (g == 0) sFac[idx][irow] = fac;

            // ---- pack P -> bf16, swizzled LDS ----
            char* pb = (char*)Pbuf[idx];
            #pragma unroll
            for (int jf = 0; jf < 4; ++jf) {
                uint2 u;
                u.x = cvt_pk_bf16(p[jf * 4 + 0], p[jf * 4 + 1]);
                u.y = cvt_pk_bf16(p[jf * 4 + 2], p[jf * 4 + 3]);
                *(uint2*)(pb + pwoff[jf]) = u;
            }
        } else if (!isProd) {
            const bool doV = (jt >= 1 && jt < 64);
            const bool doK = (jt < 63);

            // ---- issue V loads for NEXT PV (tile jt) ----
            uint4 vnext[8];
            if (doV) {
                #pragma unroll
                for (int cf = 0; cf < 4; ++cf) {
                    vnext[cf * 2]     = *(const uint4*)&vbase[cf][jt * 64 + g * 8];
                    vnext[cf * 2 + 1] = *(const uint4*)&vbase[cf][jt * 64 + 32 + g * 8];
                }
            }
            // ---- issue K loads for tile jt+1 ----
            uint4 pk0, pk1;
            if (doK) {
                const size_t rb = kpf_base + (size_t)(jt + 1) * 64 * CQK;
                pk0 = *(const uint4*)&kpfx[rb];
                pk1 = *(const uint4*)&kpfx[rb + 32 * CQK];
            }

            // ---- PV on tile jt-1 ----
            if (jt >= 1) {
                const char* pb = (const char*)Pbuf[idx ^ 1];
                short8 pf[4][2];
                float  ff[4];
                #pragma unroll
                for (int f = 0; f < 4; ++f) {
                    pf[f][0] = __builtin_bit_cast(short8, *(const uint4*)(pb + pr_off[f][0]));
                    pf[f][1] = __builtin_bit_cast(short8, *(const uint4*)(pb + pr_off[f][1]));
                    ff[f] = sFac[idx ^ 1][f * 16 + m];
                }
                if (!__all(ff[0] == 1.f && ff[1] == 1.f && ff[2] == 1.f && ff[3] == 1.f)) {
                    #pragma unroll
                    for (int cf = 0; cf < 4; ++cf)
                        #pragma unroll
                        for (int f = 0; f < 4; ++f) acc[cf][f] *= ff[f];
                }
                __builtin_amdgcn_s_setprio(1);
                #pragma unroll
                for (int cf = 0; cf < 4; ++cf) {
                    short8 v0 = __builtin_bit_cast(short8, vcur[cf * 2]);
                    short8 v1 = __builtin_bit_cast(short8, vcur[cf * 2 + 1]);
                    #pragma unroll
                    for (int f = 0; f < 4; ++f) {
                        f32x4 a = acc[cf][f];
                        a = __builtin_amdgcn_mfma_f32_16x16x32_bf16(v0, pf[f][0], a, 0, 0, 0);
                        a = __builtin_amdgcn_mfma_f32_16x16x32_bf16(v1, pf[f][1], a, 0, 0, 0);
                        acc[cf][f] = a;
                    }
                }
                __builtin_amdgcn_s_setprio(0);
            }

            // ---- write prefetched K tile ----
            if (doK) {
                *(uint4*)&Ksw[idx ^ 1][kwr0] = pk0;
                *(uint4*)&Ksw[idx ^ 1][kwr1] = pk1;
            }
            if (doV) {
                #pragma unroll
                for (int k = 0; k < 8; ++k) vcur[k] = vnext[k];
            }
        }

        __syncthreads();
    }

    // ---- epilogue ----
    if (isProd) {
        if (g == 0) sL[irow] = l_run;
    }
    __syncthreads();
    if (!isProd) {
        const float gm = gamma[0];
        #pragma unroll
        for (int f = 0; f < 4; ++f) {
            float linv = 1.0f / sL[f * 16 + m];
            #pragma unroll
            for (int cf = 0; cf < 4; ++cf) {
                #pragma unroll
                for (int r = 0; r < 4; ++r) {
                    int c = w * 64 + cf * 16 + g * 4 + r;
                    size_t o = ((size_t)b * CH + c) * NPIX + i0 + f * 16 + m;
                    out[o] = gm * acc[cf][f][r] * linv + x[o];
                }
            }
        }
    }
}

extern "C" void kernel_launch(void* const* d_in, const int* in_sizes, int n_in,
                              void* d_out, int out_size, void* d_ws, size_t ws_size,
                              hipStream_t stream) {
    const float* x     = (const float*)d_in[0];
    const float* wq    = (const float*)d_in[1];
    const float* bq    = (const float*)d_in[2];
    const float* wk    = (const float*)d_in[3];
    const float* bk    = (const float*)d_in[4];
    const float* bv    = (const float*)d_in[6];
    const float* wv    = (const float*)d_in[5];
    const float* gamma = (const float*)d_in[7];
    float* out = (float*)d_out;

    // ws layout (bf16): Qh|Ql|Kh|Kl (1MB each) | Vb (8MB) | Wh|Wl (160KB each)
    unsigned short* base = (unsigned short*)d_ws;
    const size_t qk_sz = (size_t)BATCH * NPIX * CQK;   // 524288
    unsigned short* Qh = base;
    unsigned short* Ql = Qh + qk_sz;
    unsigned short* Kh = Ql + qk_sz;
    unsigned short* Kl = Kh + qk_sz;
    unsigned short* Vb = Kl + qk_sz;
    unsigned short* Wh = Vb + (size_t)BATCH * CH * NPIX;
    unsigned short* Wl = Wh + 320 * 256;

    wcvt_kernel<<<320, 256, 0, stream>>>(wq, wk, wv, Wh, Wl);
    qkv_kernel<<<dim3(128, 4), 256, 0, stream>>>(x, bq, bk, bv, Wh, Wl,
                                                 Qh, Ql, Kh, Kl, Vb);
    attn_kernel<<<256, 512, 0, stream>>>(Qh, Ql, Kh, Kl, Vb, x, gamma, out);
}